// Round 4
// baseline (960.875 us; speedup 1.0000x reference)
//
#include <hip/hip_runtime.h>

#define N_TOK  65536
#define N_CODE 8192
#define DIM    256

typedef _Float16 f16;
typedef _Float16 f16x8 __attribute__((ext_vector_type(8)));
typedef float    f32x16 __attribute__((ext_vector_type(16)));

// ---------- kernel 1: row sum-of-squares (one wave per row) ----------
// NOTE: summation order (float4 sequential + shfl_down tree) bit-matches the
// reference fp32 reduction — do not change.
__global__ __launch_bounds__(256) void rowsq_kernel(const float* __restrict__ src,
                                                    float* __restrict__ dst, int nrows) {
    int row  = blockIdx.x * 4 + (threadIdx.x >> 6);
    int lane = threadIdx.x & 63;
    if (row >= nrows) return;
    float4 v = ((const float4*)(src + (size_t)row * DIM))[lane];
    float s = v.x * v.x + v.y * v.y + v.z * v.z + v.w * v.w;
#pragma unroll
    for (int off = 32; off; off >>= 1) s += __shfl_down(s, off, 64);
    if (lane == 0) dst[row] = s;
}

// ---------- kernel 2: split W into 2 fp16 limbs (pre-scaled, subnormal-free) ----------
__global__ __launch_bounds__(256) void splitw_kernel(const float* __restrict__ W,
                                                     f16* __restrict__ W1,
                                                     f16* __restrict__ W2) {
    int f = blockIdx.x * 256 + threadIdx.x;          // float4 id
    float4 v = ((const float4*)W)[f];
    union { f16 h[4]; uint2 u; } p1, p2;
    float e[4] = {v.x, v.y, v.z, v.w};
#pragma unroll
    for (int i = 0; i < 4; ++i) {
        float ws = e[i] * 16384.0f;                  // exact (pow2)
        f16 w1 = (f16)ws;                            // RNE
        float r = (ws - (float)w1) * 2048.0f;        // exact
        p1.h[i] = w1; p2.h[i] = (f16)r;
    }
    ((uint2*)W1)[f] = p1.u;
    ((uint2*)W2)[f] = p2.u;
}

// ---------- kernel 3: fused MFMA GEMM + argmin, v6 ----------
// v4 structure verbatim (512 blocks x 256 thr, 2 blocks/CU, XOR-staged LDS
// double-buffer — 654us proven; v5's lane-linear layout zeroed bank conflicts
// but scattered the staging globals and regressed to 730us -> reverted).
// v6 single change: MFMA shape 16x16x32 -> 32x32x16 (ubench 2075 -> 2382 TF,
// 1.19x FLOP/cy for identical math). Wave owns 32tok x 32code C-tile; same
// 32 ds_read_b128/wave-tile (same bytes, same XOR addressing, b1/b2 share an
// address reg via +16384 imm); MFMA count 96 -> 48 at 2x FLOP each.
// C/D map (m74/m101): col=lane&31, row=(reg&3)+8*(reg>>2)+4*(lane>>5).
// Per-ks accumulation order (main; a2*b1; a1*b2) matches v4's per-s order.
__global__ __launch_bounds__(256, 2) void argmin_mfma6(
    const float* __restrict__ X, const f16* __restrict__ W1, const f16* __restrict__ W2,
    const float* __restrict__ sxq, const float* __restrict__ esq,
    int* __restrict__ out_idx) {

    __shared__ char wbuf[65536];   // [sel:2][limb:2][16KB]

    const int tid  = threadIdx.x;
    const int lane = tid & 63;
    const int wv   = tid >> 6;        // 0..3
    const int col  = lane & 31;       // code col (B) / token row (A) within 32
    const int hi   = lane >> 5;       // k-octet half (0..1)
    const int wavetok0 = blockIdx.x * 128 + wv * 32;

    // ---- A: load 32 tokens x 256 dims, split to 2 f16 limbs, keep in regs ----
    // frag ks: lane holds X[wavetok0 + col][ks*16 + hi*8 + j], j=0..7
    f16x8 a1[16], a2[16];
#pragma unroll
    for (int ks = 0; ks < 16; ++ks) {
        const float* p = X + (size_t)(wavetok0 + col) * DIM + ks * 16 + hi * 8;
        float4 v0 = ((const float4*)p)[0];
        float4 v1 = ((const float4*)p)[1];
        float e[8] = {v0.x, v0.y, v0.z, v0.w, v1.x, v1.y, v1.z, v1.w};
#pragma unroll
        for (int j = 0; j < 8; ++j) {
            f16 h = (f16)e[j];
            float r = (e[j] - (float)h) * 2048.0f;   // exact
            a1[ks][j] = h;
            a2[ks][j] = (f16)r;
        }
    }

    // sx for this lane's 16 token slots: reg r -> token (r&3) + 8*(r>>2) + 4*hi
    float sxr[16];
#pragma unroll
    for (int r = 0; r < 16; ++r)
        sxr[r] = sxq[wavetok0 + (r & 3) + 8 * (r >> 2) + 4 * hi];

    float bestd[16];
    int   besti[16];
#pragma unroll
    for (int i = 0; i < 16; ++i) { bestd[i] = 3.4e38f; besti[i] = 0x7fffffff; }

    // ---- staging (v4 verbatim): 32KB per ct (2 limbs x 32 codes x 512B),
    // 32 wave-instrs, 8/wave. lane i of instr fi: c = 2*cp + (i>>5),
    // o = (i&31) ^ (c&7)  -> LDS granule(c,o) = c*32 + (o ^ (c&7)).
    auto stage = [&](int ct2, int sel) {
#pragma unroll
        for (int t = 0; t < 8; ++t) {
            int fi = wv * 8 + t;
            int L  = fi >> 4;             // limb
            int cp = fi & 15;             // code pair
            int c  = 2 * cp + (lane >> 5);
            int o  = (lane & 31) ^ (c & 7);
            const f16* gsrc = (L ? W2 : W1) + (size_t)(ct2 * 32 + c) * DIM + o * 8;
            char* ldst = wbuf + sel * 32768 + L * 16384 + cp * 1024;
            __builtin_amdgcn_global_load_lds(
                (const __attribute__((address_space(1))) unsigned int*)gsrc,
                (__attribute__((address_space(3))) unsigned int*)ldst, 16, 0, 0);
        }
    };

    stage(0, 0);
    __syncthreads();

    const int x7 = col & 7;

    for (int ct = 0; ct < N_CODE / 32; ++ct) {
        if (ct + 1 < N_CODE / 32) stage(ct + 1, (ct + 1) & 1);

        float se = esq[ct * 32 + col];

        f32x16 mainA, cross;
#pragma unroll
        for (int r = 0; r < 16; ++r) { mainA[r] = 0.f; cross[r] = 0.f; }

        // row base for this lane's code column; limb is a +16384 immediate.
        const char* lbase = wbuf + (ct & 1) * 32768 + col * 512;
#pragma unroll
        for (int ks = 0; ks < 16; ++ks) {
            int perm = ((ks * 2 + hi) ^ x7) << 4;    // XOR granule within row
            f16x8 b1 = *(const f16x8*)(lbase + perm);
            f16x8 b2 = *(const f16x8*)(lbase + 16384 + perm);
            __builtin_amdgcn_s_setprio(1);
            mainA = __builtin_amdgcn_mfma_f32_32x32x16_f16(a1[ks], b1, mainA, 0, 0, 0);
            cross = __builtin_amdgcn_mfma_f32_32x32x16_f16(a2[ks], b1, cross, 0, 0, 0);
            cross = __builtin_amdgcn_mfma_f32_32x32x16_f16(a1[ks], b2, cross, 0, 0, 0);
            __builtin_amdgcn_s_setprio(0);
        }

        // epilogue: d = fl(fl(sx+se) - 2*dot); dot*2^14 = main + 2^-11*cross
        // one candidate per (lane, slot) per tile, code = ct*32 + col ascending
        // in ct: strict < keeps lowest index.
#pragma unroll
        for (int r = 0; r < 16; ++r) {
            float mc = fmaf(cross[r], 4.8828125e-4f, mainA[r]);   // *2^-11
            float t1 = sxr[r] + se;
            float d  = fmaf(-1.220703125e-4f, mc, t1);            // -2^-13
            if (d < bestd[r]) {
                bestd[r] = d;
                besti[r] = ct * 32 + col;
            }
        }
        __syncthreads();
    }

    // ---- cross-lane reduction over the 32 code-lanes (lex (d, idx) min) ----
    // lanes with equal hi hold the same token rows; reduce within each half.
#pragma unroll
    for (int r = 0; r < 16; ++r) {
        float d = bestd[r];
        int   i = besti[r];
#pragma unroll
        for (int off = 1; off < 32; off <<= 1) {
            float od = __shfl_xor(d, off, 64);
            int   oi = __shfl_xor(i, off, 64);
            if (od < d || (od == d && oi < i)) { d = od; i = oi; }
        }
        if (col == 0)
            out_idx[wavetok0 + (r & 3) + 8 * (r >> 2) + 4 * hi] = i;
    }
}

// ---------- kernel 4: gather + straight-through output + loss partials ----------
// atomic spread over 128 accumulators (v4: cut same-address f64 atomic chain
// from 16384 deep to ~128; non-argmin tail 236us -> ~100us).
__global__ __launch_bounds__(256) void finalize_kernel(
    const float* __restrict__ X, const float* __restrict__ W,
    const int* __restrict__ idx, float* __restrict__ outQ,
    float* __restrict__ outI, double* __restrict__ accum) {
    __shared__ double wsum[4];
    int wid  = threadIdx.x >> 6;
    int lane = threadIdx.x & 63;
    int token = blockIdx.x * 4 + wid;
    int id = idx[token];
    float4 x = ((const float4*)(X + (size_t)token * DIM))[lane];
    float4 qv = ((const float4*)(W + (size_t)id * DIM))[lane];
    float4 o;
    o.x = x.x + (qv.x - x.x);
    o.y = x.y + (qv.y - x.y);
    o.z = x.z + (qv.z - x.z);
    o.w = x.w + (qv.w - x.w);
    ((float4*)(outQ + (size_t)token * DIM))[lane] = o;
    float dx = x.x - qv.x, dy = x.y - qv.y, dz = x.z - qv.z, dw = x.w - qv.w;
    float s = dx * dx + dy * dy + dz * dz + dw * dw;
#pragma unroll
    for (int off = 32; off; off >>= 1) s += __shfl_down(s, off, 64);
    if (lane == 0) {
        outI[token] = (float)id;
        wsum[wid] = (double)s;
    }
    __syncthreads();
    if (threadIdx.x == 0) {
        double t = wsum[0] + wsum[1] + wsum[2] + wsum[3];
        atomicAdd(&accum[blockIdx.x & 127], t);
    }
}

// ---------- kernel 5: scalars ----------
__global__ void scalars_kernel(const double* __restrict__ accum, float* __restrict__ out) {
    double mse = 0.0;
    for (int i = 0; i < 128; ++i) mse += accum[i];
    mse /= (double)((size_t)N_TOK * DIM);
    float c = (float)mse;
    out[0] = c + 0.25f * c;
    out[1] = c;
    out[2] = c;
}

extern "C" void kernel_launch(void* const* d_in, const int* in_sizes, int n_in,
                              void* d_out, int out_size, void* d_ws, size_t ws_size,
                              hipStream_t stream) {
    const float* X = (const float*)d_in[0];   // (65536, 256)
    const float* W = (const float*)d_in[1];   // (8192, 256)

    float* outQ = (float*)d_out;
    float* outI = outQ + (size_t)N_TOK * DIM;
    float* outS = outI + N_TOK;

    char* ws = (char*)d_ws;
    double* accum = (double*)ws;                         // @0, 1 KB (128 doubles)
    float* esq = (float*)(ws + 4096);                    // 32 KB
    float* sxq = (float*)(ws + 4096 + 32768);            // 256 KB
    int*   idx = (int*)(ws + 4096 + 32768 + 262144);     // 256 KB
    f16*   W1  = (f16*)(ws + (1 << 20));                 // 4 MB
    f16*   W2  = (f16*)(ws + (1 << 20) + 4194304);       // 4 MB

    hipMemsetAsync(accum, 0, 128 * sizeof(double), stream);
    splitw_kernel<<<N_CODE * DIM / 4 / 256, 256, 0, stream>>>(W, W1, W2);
    rowsq_kernel<<<N_CODE / 4, 256, 0, stream>>>(W, esq, N_CODE);
    rowsq_kernel<<<N_TOK / 4, 256, 0, stream>>>(X, sxq, N_TOK);
    argmin_mfma6<<<N_TOK / 128, 256, 0, stream>>>(X, W1, W2, sxq, esq, idx);
    finalize_kernel<<<N_TOK / 4, 256, 0, stream>>>(X, W, idx, outQ, outI, accum);
    scalars_kernel<<<1, 1, 0, stream>>>(accum, outS);
}

// Round 5
// 764.623 us; speedup vs baseline: 1.2567x; 1.2567x over previous
//
#include <hip/hip_runtime.h>

#define N_TOK  65536
#define N_CODE 8192
#define DIM    256

typedef _Float16 f16;
typedef _Float16 f16x8 __attribute__((ext_vector_type(8)));
typedef float    f32x4 __attribute__((ext_vector_type(4)));

// ---------- kernel 1: row sum-of-squares (one wave per row) ----------
// NOTE: summation order (float4 sequential + shfl_down tree) bit-matches the
// reference fp32 reduction — do not change.
__global__ __launch_bounds__(256) void rowsq_kernel(const float* __restrict__ src,
                                                    float* __restrict__ dst, int nrows) {
    int row  = blockIdx.x * 4 + (threadIdx.x >> 6);
    int lane = threadIdx.x & 63;
    if (row >= nrows) return;
    float4 v = ((const float4*)(src + (size_t)row * DIM))[lane];
    float s = v.x * v.x + v.y * v.y + v.z * v.z + v.w * v.w;
#pragma unroll
    for (int off = 32; off; off >>= 1) s += __shfl_down(s, off, 64);
    if (lane == 0) dst[row] = s;
}

// ---------- kernel 2: split W into 2 fp16 limbs (pre-scaled, subnormal-free) ----------
__global__ __launch_bounds__(256) void splitw_kernel(const float* __restrict__ W,
                                                     f16* __restrict__ W1,
                                                     f16* __restrict__ W2) {
    int f = blockIdx.x * 256 + threadIdx.x;          // float4 id
    float4 v = ((const float4*)W)[f];
    union { f16 h[4]; uint2 u; } p1, p2;
    float e[4] = {v.x, v.y, v.z, v.w};
#pragma unroll
    for (int i = 0; i < 4; ++i) {
        float ws = e[i] * 16384.0f;                  // exact (pow2)
        f16 w1 = (f16)ws;                            // RNE
        float r = (ws - (float)w1) * 2048.0f;        // exact
        p1.h[i] = w1; p2.h[i] = (f16)r;
    }
    ((uint2*)W1)[f] = p1.u;
    ((uint2*)W2)[f] = p2.u;
}

// ---------- kernel 3: fused MFMA GEMM + argmin, v7 ----------
// v4 structure verbatim (512 blocks x 256 thr, 2 blocks/CU, 16x16x32, 654us;
// v6's 32x32 shape spilled: +24 regs of epilogue state > 256-reg cap ->
// WRITE_SIZE 11.5MB scratch -> reverted). v7: VALU diet. Counters said
// MFMA(62%)+VALU(33%) ~ issue-saturated; ~130 VALU/wave-tile was address
// math. Same addresses, same access & MFMA order — only cheaper arithmetic:
//  - ds_read: granule (s*4+q)^(cl&7) == ((s^b)<<2)|qx with per-lane consts
//    qx=q^(x7&3), b=x7>>2; bits6-8 of base are 0 => addr = Bx ^ (s<<6),
//    ONE v_xor per s; all 4 frags (b1/b2 x nt) via imm offsets
//    {0,8192,16384,24576} off one vaddr.
//  - staging: lane part = VL ^ ((t&3)<<5), VL = l5*512 + ((lane31^l5)<<4),
//    4 variants precomputed once; per-tile staging is base adds only.
// Bit-identical output to v4 (verified formula equivalence on sample lanes).
__global__ __launch_bounds__(256, 2) void argmin_mfma7(
    const float* __restrict__ X, const f16* __restrict__ W1, const f16* __restrict__ W2,
    const float* __restrict__ sxq, const float* __restrict__ esq,
    int* __restrict__ out_idx) {

    __shared__ char wbuf[65536];   // [sel:2][limb:2][16KB]

    const int tid  = threadIdx.x;
    const int lane = tid & 63;
    const int wv   = tid >> 6;        // 0..3
    const int cl   = lane & 15;       // code-col / token-row within 16
    const int q    = lane >> 4;       // 0..3 k-octet
    const int l5   = lane >> 5;       // 0..1
    const int lane31 = lane & 31;
    const int x7   = cl & 7;
    const int wavetok0 = blockIdx.x * 128 + wv * 32;

    // ---- A: load 32 tokens x 256 dims, split to 2 f16 limbs, keep in regs ----
    // frag (mt, s): lane holds X[wavetok0 + mt*16 + cl][s*32 + q*8 + j], j=0..7
    f16x8 a1[2][8], a2[2][8];
#pragma unroll
    for (int mt = 0; mt < 2; ++mt)
#pragma unroll
        for (int s = 0; s < 8; ++s) {
            const float* p = X + (size_t)(wavetok0 + mt * 16 + cl) * DIM + s * 32 + q * 8;
            float4 v0 = ((const float4*)p)[0];
            float4 v1 = ((const float4*)p)[1];
            float e[8] = {v0.x, v0.y, v0.z, v0.w, v1.x, v1.y, v1.z, v1.w};
#pragma unroll
            for (int j = 0; j < 8; ++j) {
                f16 h = (f16)e[j];
                float r = (e[j] - (float)h) * 2048.0f;   // exact
                a1[mt][s][j] = h;
                a2[mt][s][j] = (f16)r;
            }
        }

    // sx for this lane's 8 token slots: slot = mt*4+r -> token mt*16 + q*4 + r
    float sxr[8];
#pragma unroll
    for (int mt = 0; mt < 2; ++mt)
#pragma unroll
        for (int r = 0; r < 4; ++r)
            sxr[mt * 4 + r] = sxq[wavetok0 + mt * 16 + q * 4 + r];

    float bestd[8];
    int   besti[8];
#pragma unroll
    for (int i = 0; i < 8; ++i) { bestd[i] = 3.4e38f; besti[i] = 0x7fffffff; }

    // ---- precomputed address constants ----
    // ds_read: base Bx (bits 6-8 clear except b at bit6), per-s addr = Bx ^ (s<<6)
    const int qx = q ^ (x7 & 3);
    const int Bx = cl * 512 + qx * 16 + ((x7 >> 2) << 6);
    // staging lane part: VL ^ ((cp&3)<<5), cp&3 == t&3
    const int VL = l5 * 512 + (((lane31 ^ l5)) << 4);
    const int vstg0 = VL;
    const int vstg1 = VL ^ 32;
    const int vstg2 = VL ^ 64;
    const int vstg3 = VL ^ 96;

    // ---- staging (same addresses as v4): 32KB per ct, 32 wave-instrs, 8/wave.
    auto stage = [&](int ct2, int sel) {
        const char* g1 = (const char*)W1 + ct2 * 16384;
        const char* g2 = (const char*)W2 + ct2 * 16384;
#pragma unroll
        for (int t = 0; t < 8; ++t) {
            int fi = wv * 8 + t;
            int L  = fi >> 4;             // limb (wave-uniform)
            int cp = fi & 15;             // code pair (wave-uniform)
            int vs = (t & 3) == 0 ? vstg0 : (t & 3) == 1 ? vstg1 : (t & 3) == 2 ? vstg2 : vstg3;
            const char* gsrc = (L ? g2 : g1) + cp * 1024 + vs;
            char* ldst = wbuf + sel * 32768 + L * 16384 + cp * 1024;
            __builtin_amdgcn_global_load_lds(
                (const __attribute__((address_space(1))) unsigned int*)gsrc,
                (__attribute__((address_space(3))) unsigned int*)ldst, 16, 0, 0);
        }
    };

    stage(0, 0);
    __syncthreads();

    for (int ct = 0; ct < N_CODE / 32; ++ct) {
        if (ct + 1 < N_CODE / 32) stage(ct + 1, (ct + 1) & 1);

        float se0 = esq[ct * 32 + cl];
        float se1 = esq[ct * 32 + 16 + cl];

        f32x4 mainA[2][2], cross[2][2];
#pragma unroll
        for (int mt = 0; mt < 2; ++mt)
#pragma unroll
            for (int nt = 0; nt < 2; ++nt) {
                mainA[mt][nt] = (f32x4){0.f, 0.f, 0.f, 0.f};
                cross[mt][nt] = (f32x4){0.f, 0.f, 0.f, 0.f};
            }

        const int vA = Bx + ((ct & 1) << 15);
#pragma unroll
        for (int s = 0; s < 8; ++s) {
            // one vaddr per s; 4 fragments via imm offsets (same bytes as v4)
            const char* va = wbuf + (vA ^ (s << 6));
            f16x8 b1[2], b2[2];
            b1[0] = *(const f16x8*)(va);
            b1[1] = *(const f16x8*)(va + 8192);
            b2[0] = *(const f16x8*)(va + 16384);
            b2[1] = *(const f16x8*)(va + 24576);
            __builtin_amdgcn_s_setprio(1);
#pragma unroll
            for (int mt = 0; mt < 2; ++mt)
#pragma unroll
                for (int nt = 0; nt < 2; ++nt) {
                    mainA[mt][nt] = __builtin_amdgcn_mfma_f32_16x16x32_f16(a1[mt][s], b1[nt], mainA[mt][nt], 0, 0, 0);
                    cross[mt][nt] = __builtin_amdgcn_mfma_f32_16x16x32_f16(a2[mt][s], b1[nt], cross[mt][nt], 0, 0, 0);
                    cross[mt][nt] = __builtin_amdgcn_mfma_f32_16x16x32_f16(a1[mt][s], b2[nt], cross[mt][nt], 0, 0, 0);
                }
            __builtin_amdgcn_s_setprio(0);
        }

        // epilogue: d = fl(fl(sx+se) - 2*dot); dot*2^14 = main + 2^-11*cross
        // per lane, candidates ascend in code (nt inner, ct outer): strict < keeps lowest.
#pragma unroll
        for (int mt = 0; mt < 2; ++mt)
#pragma unroll
            for (int nt = 0; nt < 2; ++nt)
#pragma unroll
                for (int r = 0; r < 4; ++r) {
                    float mc = fmaf(cross[mt][nt][r], 4.8828125e-4f, mainA[mt][nt][r]);  // *2^-11
                    float t1 = sxr[mt * 4 + r] + (nt ? se1 : se0);
                    float d  = fmaf(-1.220703125e-4f, mc, t1);                          // -2^-13
                    int slot = mt * 4 + r;
                    if (d < bestd[slot]) {
                        bestd[slot] = d;
                        besti[slot] = ct * 32 + nt * 16 + cl;
                    }
                }
        __syncthreads();
    }

    // ---- cross-lane reduction over the 16 code-lanes (lex (d, idx) min) ----
#pragma unroll
    for (int slot = 0; slot < 8; ++slot) {
        float d = bestd[slot];
        int   i = besti[slot];
#pragma unroll
        for (int off = 1; off < 16; off <<= 1) {
            float od = __shfl_xor(d, off, 64);
            int   oi = __shfl_xor(i, off, 64);
            if (od < d || (od == d && oi < i)) { d = od; i = oi; }
        }
        if (cl == 0)
            out_idx[wavetok0 + (slot >> 2) * 16 + q * 4 + (slot & 3)] = i;
    }
}

// ---------- kernel 4: gather + straight-through output + loss partials ----------
// atomic spread over 128 accumulators (v4: cut same-address f64 atomic chain
// from 16384 deep to ~128; non-argmin tail 236us -> ~100us).
__global__ __launch_bounds__(256) void finalize_kernel(
    const float* __restrict__ X, const float* __restrict__ W,
    const int* __restrict__ idx, float* __restrict__ outQ,
    float* __restrict__ outI, double* __restrict__ accum) {
    __shared__ double wsum[4];
    int wid  = threadIdx.x >> 6;
    int lane = threadIdx.x & 63;
    int token = blockIdx.x * 4 + wid;
    int id = idx[token];
    float4 x = ((const float4*)(X + (size_t)token * DIM))[lane];
    float4 qv = ((const float4*)(W + (size_t)id * DIM))[lane];
    float4 o;
    o.x = x.x + (qv.x - x.x);
    o.y = x.y + (qv.y - x.y);
    o.z = x.z + (qv.z - x.z);
    o.w = x.w + (qv.w - x.w);
    ((float4*)(outQ + (size_t)token * DIM))[lane] = o;
    float dx = x.x - qv.x, dy = x.y - qv.y, dz = x.z - qv.z, dw = x.w - qv.w;
    float s = dx * dx + dy * dy + dz * dz + dw * dw;
#pragma unroll
    for (int off = 32; off; off >>= 1) s += __shfl_down(s, off, 64);
    if (lane == 0) {
        outI[token] = (float)id;
        wsum[wid] = (double)s;
    }
    __syncthreads();
    if (threadIdx.x == 0) {
        double t = wsum[0] + wsum[1] + wsum[2] + wsum[3];
        atomicAdd(&accum[blockIdx.x & 127], t);
    }
}

// ---------- kernel 5: scalars ----------
__global__ void scalars_kernel(const double* __restrict__ accum, float* __restrict__ out) {
    double mse = 0.0;
    for (int i = 0; i < 128; ++i) mse += accum[i];
    mse /= (double)((size_t)N_TOK * DIM);
    float c = (float)mse;
    out[0] = c + 0.25f * c;
    out[1] = c;
    out[2] = c;
}

extern "C" void kernel_launch(void* const* d_in, const int* in_sizes, int n_in,
                              void* d_out, int out_size, void* d_ws, size_t ws_size,
                              hipStream_t stream) {
    const float* X = (const float*)d_in[0];   // (65536, 256)
    const float* W = (const float*)d_in[1];   // (8192, 256)

    float* outQ = (float*)d_out;
    float* outI = outQ + (size_t)N_TOK * DIM;
    float* outS = outI + N_TOK;

    char* ws = (char*)d_ws;
    double* accum = (double*)ws;                         // @0, 1 KB (128 doubles)
    float* esq = (float*)(ws + 4096);                    // 32 KB
    float* sxq = (float*)(ws + 4096 + 32768);            // 256 KB
    int*   idx = (int*)(ws + 4096 + 32768 + 262144);     // 256 KB
    f16*   W1  = (f16*)(ws + (1 << 20));                 // 4 MB
    f16*   W2  = (f16*)(ws + (1 << 20) + 4194304);       // 4 MB

    hipMemsetAsync(accum, 0, 128 * sizeof(double), stream);
    splitw_kernel<<<N_CODE * DIM / 4 / 256, 256, 0, stream>>>(W, W1, W2);
    rowsq_kernel<<<N_CODE / 4, 256, 0, stream>>>(W, esq, N_CODE);
    rowsq_kernel<<<N_TOK / 4, 256, 0, stream>>>(X, sxq, N_TOK);
    argmin_mfma7<<<N_TOK / 128, 256, 0, stream>>>(X, W1, W2, sxq, esq, idx);
    finalize_kernel<<<N_TOK / 4, 256, 0, stream>>>(X, W, idx, outQ, outI, accum);
    scalars_kernel<<<1, 1, 0, stream>>>(accum, outS);
}

// Round 6
// 745.103 us; speedup vs baseline: 1.2896x; 1.0262x over previous
//
#include <hip/hip_runtime.h>

#define N_TOK  65536
#define N_CODE 8192
#define DIM    256

typedef _Float16 f16;
typedef _Float16 f16x8 __attribute__((ext_vector_type(8)));
typedef float    f32x4 __attribute__((ext_vector_type(4)));

// ---------- kernel 1: row sum-of-squares (one wave per row) ----------
// NOTE: summation order (float4 sequential + shfl_down tree) bit-matches the
// reference fp32 reduction — do not change.
__global__ __launch_bounds__(256) void rowsq_kernel(const float* __restrict__ src,
                                                    float* __restrict__ dst, int nrows) {
    int row  = blockIdx.x * 4 + (threadIdx.x >> 6);
    int lane = threadIdx.x & 63;
    if (row >= nrows) return;
    float4 v = ((const float4*)(src + (size_t)row * DIM))[lane];
    float s = v.x * v.x + v.y * v.y + v.z * v.z + v.w * v.w;
#pragma unroll
    for (int off = 32; off; off >>= 1) s += __shfl_down(s, off, 64);
    if (lane == 0) dst[row] = s;
}

// ---------- kernel 2: split W into 2 fp16 limbs, TRANSPOSED (k-major) ----------
// W1t/W2t layout: 16B granule (o, c) at byte o*131072 + c*16 holds
// W?[c][o*8 .. o*8+7]  (o = dim-octet 0..31, c = code 0..8191).
// Same limb math as before (pre-scaled, subnormal-free, exact residual).
// Writes coalesced (consecutive threads = consecutive codes); reads are 32B
// strided — volume is only 8MB, invisible.
__global__ __launch_bounds__(256) void splitw_t_kernel(const float* __restrict__ W,
                                                       f16* __restrict__ W1t,
                                                       f16* __restrict__ W2t) {
    int g = blockIdx.x * 256 + threadIdx.x;   // octet-task id, < 32*8192
    int o = g >> 13;                          // dim octet 0..31
    int c = g & 8191;                         // code
    const float* p = W + (size_t)c * DIM + o * 8;
    float4 v0 = ((const float4*)p)[0];
    float4 v1 = ((const float4*)p)[1];
    float e[8] = {v0.x, v0.y, v0.z, v0.w, v1.x, v1.y, v1.z, v1.w};
    union { f16 h[8]; uint4 u; } p1, p2;
#pragma unroll
    for (int i = 0; i < 8; ++i) {
        float ws = e[i] * 16384.0f;                  // exact (pow2)
        f16 w1 = (f16)ws;                            // RNE
        float r = (ws - (float)w1) * 2048.0f;        // exact
        p1.h[i] = w1; p2.h[i] = (f16)r;
    }
    size_t byteoff = (size_t)o * 131072 + (size_t)c * 16;
    *(uint4*)((char*)W1t + byteoff) = p1.u;
    *(uint4*)((char*)W2t + byteoff) = p2.u;
}

// ---------- kernel 3: fused MFMA GEMM + argmin, v8 ----------
// v4/v7 structure (512 blocks x 256 thr, 2 blocks/CU, 16x16x32, 649us).
// v8: conflict-free LDS via k-major codebook. v4's XOR layout paid a measured
// +4cy/b128 (6.7e7 conflict-cy = 1024 cy/CU-tile); v5 zeroed it but scattered
// staging to 64B granules (+9MB FETCH, net -76us). With W1t/W2t transposed in
// global, staging keeps 2x512B contiguous lines per instr AND reads become
// 16-lane x 256B contiguous slabs (m134's linear pattern, ~0 conflicts), with
// all fragment offsets compile-time immediates off ONE per-lane base.
// Fragment values / MFMA order / epilogue bit-identical to v4 (absmax 0.0).
// LDS layout: [sel:2][L:2][o:32][c:32] x 16B granules.
__global__ __launch_bounds__(256, 2) void argmin_mfma8(
    const float* __restrict__ X, const f16* __restrict__ W1t, const f16* __restrict__ W2t,
    const float* __restrict__ sxq, const float* __restrict__ esq,
    int* __restrict__ out_idx) {

    __shared__ char wbuf[65536];   // [sel:2][limb:2][o:32][c:32]*16B

    const int tid  = threadIdx.x;
    const int lane = tid & 63;
    const int wv   = tid >> 6;        // 0..3
    const int cl   = lane & 15;       // code-col / token-row within 16
    const int q    = lane >> 4;       // 0..3 k-octet
    const int l5   = lane >> 5;       // 0..1
    const int lane31 = lane & 31;
    const int wavetok0 = blockIdx.x * 128 + wv * 32;

    // ---- A: load 32 tokens x 256 dims, split to 2 f16 limbs, keep in regs ----
    // frag (mt, s): lane holds X[wavetok0 + mt*16 + cl][s*32 + q*8 + j], j=0..7
    f16x8 a1[2][8], a2[2][8];
#pragma unroll
    for (int mt = 0; mt < 2; ++mt)
#pragma unroll
        for (int s = 0; s < 8; ++s) {
            const float* p = X + (size_t)(wavetok0 + mt * 16 + cl) * DIM + s * 32 + q * 8;
            float4 v0 = ((const float4*)p)[0];
            float4 v1 = ((const float4*)p)[1];
            float e[8] = {v0.x, v0.y, v0.z, v0.w, v1.x, v1.y, v1.z, v1.w};
#pragma unroll
            for (int j = 0; j < 8; ++j) {
                f16 h = (f16)e[j];
                float r = (e[j] - (float)h) * 2048.0f;   // exact
                a1[mt][s][j] = h;
                a2[mt][s][j] = (f16)r;
            }
        }

    // sx for this lane's 8 token slots: slot = mt*4+r -> token mt*16 + q*4 + r
    float sxr[8];
#pragma unroll
    for (int mt = 0; mt < 2; ++mt)
#pragma unroll
        for (int r = 0; r < 4; ++r)
            sxr[mt * 4 + r] = sxq[wavetok0 + mt * 16 + q * 4 + r];

    float bestd[8];
    int   besti[8];
#pragma unroll
    for (int i = 0; i < 8; ++i) { bestd[i] = 3.4e38f; besti[i] = 0x7fffffff; }

    // ---- per-lane address constants ----
    // staging source lane part: octet parity slab + code granule
    const int SL = l5 * 131072 + lane31 * 16;
    // read base: V = q*512 + cl*16 (o = s*4+q at o*512; c = nt*16+cl at c*16)
    const char* RB = wbuf + q * 512 + cl * 16;

    // ---- staging: 32KB per ct (2 limbs x 32 octet-slabs x 512B), 32 wave-
    // instrs, 8/wave. instr fi (= wv*8+t): L = fi>>4, octet pair op = fi&15.
    // lanes 0-31 cover (o=2op, c=0..31) [512B contiguous], lanes 32-63
    // (o=2op+1, c=0..31) [512B at +128KB]. LDS dest linear = layout order.
    auto stage = [&](int ct2, int sel) {
        const char* g1 = (const char*)W1t + ct2 * 512 + SL;
        const char* g2 = (const char*)W2t + ct2 * 512 + SL;
#pragma unroll
        for (int t = 0; t < 8; ++t) {
            int fi = wv * 8 + t;
            int L  = fi >> 4;             // limb (wave-uniform)
            int op = fi & 15;             // octet pair (wave-uniform)
            const char* gsrc = (L ? g2 : g1) + op * 262144;
            char* ldst = wbuf + sel * 32768 + L * 16384 + op * 1024;
            __builtin_amdgcn_global_load_lds(
                (const __attribute__((address_space(1))) unsigned int*)gsrc,
                (__attribute__((address_space(3))) unsigned int*)ldst, 16, 0, 0);
        }
    };

    stage(0, 0);
    __syncthreads();

    for (int ct = 0; ct < N_CODE / 32; ++ct) {
        if (ct + 1 < N_CODE / 32) stage(ct + 1, (ct + 1) & 1);

        float se0 = esq[ct * 32 + cl];
        float se1 = esq[ct * 32 + 16 + cl];

        f32x4 mainA[2][2], cross[2][2];
#pragma unroll
        for (int mt = 0; mt < 2; ++mt)
#pragma unroll
            for (int nt = 0; nt < 2; ++nt) {
                mainA[mt][nt] = (f32x4){0.f, 0.f, 0.f, 0.f};
                cross[mt][nt] = (f32x4){0.f, 0.f, 0.f, 0.f};
            }

        const char* va = RB + ((ct & 1) << 15);
#pragma unroll
        for (int s = 0; s < 8; ++s) {
            // all 4 fragments: one vaddr + compile-time immediates
            f16x8 b1[2], b2[2];
            b1[0] = *(const f16x8*)(va + s * 2048);
            b1[1] = *(const f16x8*)(va + s * 2048 + 256);
            b2[0] = *(const f16x8*)(va + s * 2048 + 16384);
            b2[1] = *(const f16x8*)(va + s * 2048 + 16640);
            __builtin_amdgcn_s_setprio(1);
#pragma unroll
            for (int mt = 0; mt < 2; ++mt)
#pragma unroll
                for (int nt = 0; nt < 2; ++nt) {
                    mainA[mt][nt] = __builtin_amdgcn_mfma_f32_16x16x32_f16(a1[mt][s], b1[nt], mainA[mt][nt], 0, 0, 0);
                    cross[mt][nt] = __builtin_amdgcn_mfma_f32_16x16x32_f16(a2[mt][s], b1[nt], cross[mt][nt], 0, 0, 0);
                    cross[mt][nt] = __builtin_amdgcn_mfma_f32_16x16x32_f16(a1[mt][s], b2[nt], cross[mt][nt], 0, 0, 0);
                }
            __builtin_amdgcn_s_setprio(0);
        }

        // epilogue: d = fl(fl(sx+se) - 2*dot); dot*2^14 = main + 2^-11*cross
        // per lane, candidates ascend in code (nt inner, ct outer): strict < keeps lowest.
#pragma unroll
        for (int mt = 0; mt < 2; ++mt)
#pragma unroll
            for (int nt = 0; nt < 2; ++nt)
#pragma unroll
                for (int r = 0; r < 4; ++r) {
                    float mc = fmaf(cross[mt][nt][r], 4.8828125e-4f, mainA[mt][nt][r]);  // *2^-11
                    float t1 = sxr[mt * 4 + r] + (nt ? se1 : se0);
                    float d  = fmaf(-1.220703125e-4f, mc, t1);                          // -2^-13
                    int slot = mt * 4 + r;
                    if (d < bestd[slot]) {
                        bestd[slot] = d;
                        besti[slot] = ct * 32 + nt * 16 + cl;
                    }
                }
        __syncthreads();
    }

    // ---- cross-lane reduction over the 16 code-lanes (lex (d, idx) min) ----
#pragma unroll
    for (int slot = 0; slot < 8; ++slot) {
        float d = bestd[slot];
        int   i = besti[slot];
#pragma unroll
        for (int off = 1; off < 16; off <<= 1) {
            float od = __shfl_xor(d, off, 64);
            int   oi = __shfl_xor(i, off, 64);
            if (od < d || (od == d && oi < i)) { d = od; i = oi; }
        }
        if (cl == 0)
            out_idx[wavetok0 + (slot >> 2) * 16 + q * 4 + (slot & 3)] = i;
    }
}

// ---------- kernel 4: gather + straight-through output + loss partials ----------
// atomic spread over 128 accumulators (v4: cut same-address f64 atomic chain
// from 16384 deep to ~128; non-argmin tail 236us -> ~100us).
__global__ __launch_bounds__(256) void finalize_kernel(
    const float* __restrict__ X, const float* __restrict__ W,
    const int* __restrict__ idx, float* __restrict__ outQ,
    float* __restrict__ outI, double* __restrict__ accum) {
    __shared__ double wsum[4];
    int wid  = threadIdx.x >> 6;
    int lane = threadIdx.x & 63;
    int token = blockIdx.x * 4 + wid;
    int id = idx[token];
    float4 x = ((const float4*)(X + (size_t)token * DIM))[lane];
    float4 qv = ((const float4*)(W + (size_t)id * DIM))[lane];
    float4 o;
    o.x = x.x + (qv.x - x.x);
    o.y = x.y + (qv.y - x.y);
    o.z = x.z + (qv.z - x.z);
    o.w = x.w + (qv.w - x.w);
    ((float4*)(outQ + (size_t)token * DIM))[lane] = o;
    float dx = x.x - qv.x, dy = x.y - qv.y, dz = x.z - qv.z, dw = x.w - qv.w;
    float s = dx * dx + dy * dy + dz * dz + dw * dw;
#pragma unroll
    for (int off = 32; off; off >>= 1) s += __shfl_down(s, off, 64);
    if (lane == 0) {
        outI[token] = (float)id;
        wsum[wid] = (double)s;
    }
    __syncthreads();
    if (threadIdx.x == 0) {
        double t = wsum[0] + wsum[1] + wsum[2] + wsum[3];
        atomicAdd(&accum[blockIdx.x & 127], t);
    }
}

// ---------- kernel 5: scalars ----------
__global__ void scalars_kernel(const double* __restrict__ accum, float* __restrict__ out) {
    double mse = 0.0;
    for (int i = 0; i < 128; ++i) mse += accum[i];
    mse /= (double)((size_t)N_TOK * DIM);
    float c = (float)mse;
    out[0] = c + 0.25f * c;
    out[1] = c;
    out[2] = c;
}

extern "C" void kernel_launch(void* const* d_in, const int* in_sizes, int n_in,
                              void* d_out, int out_size, void* d_ws, size_t ws_size,
                              hipStream_t stream) {
    const float* X = (const float*)d_in[0];   // (65536, 256)
    const float* W = (const float*)d_in[1];   // (8192, 256)

    float* outQ = (float*)d_out;
    float* outI = outQ + (size_t)N_TOK * DIM;
    float* outS = outI + N_TOK;

    char* ws = (char*)d_ws;
    double* accum = (double*)ws;                         // @0, 1 KB (128 doubles)
    float* esq = (float*)(ws + 4096);                    // 32 KB
    float* sxq = (float*)(ws + 4096 + 32768);            // 256 KB
    int*   idx = (int*)(ws + 4096 + 32768 + 262144);     // 256 KB
    f16*   W1t = (f16*)(ws + (1 << 20));                 // 4 MB (k-major)
    f16*   W2t = (f16*)(ws + (1 << 20) + 4194304);       // 4 MB (k-major)

    hipMemsetAsync(accum, 0, 128 * sizeof(double), stream);
    splitw_t_kernel<<<N_CODE * 32 / 256, 256, 0, stream>>>(W, W1t, W2t);
    rowsq_kernel<<<N_CODE / 4, 256, 0, stream>>>(W, esq, N_CODE);
    rowsq_kernel<<<N_TOK / 4, 256, 0, stream>>>(X, sxq, N_TOK);
    argmin_mfma8<<<N_TOK / 128, 256, 0, stream>>>(X, W1t, W2t, sxq, esq, idx);
    finalize_kernel<<<N_TOK / 4, 256, 0, stream>>>(X, W, idx, outQ, outI, accum);
    scalars_kernel<<<1, 1, 0, stream>>>(accum, outS);
}